// Round 9
// baseline (813.865 us; speedup 1.0000x reference)
//
#include <hip/hip_runtime.h>
#include <math.h>

#define D 128
#define EPSF 1e-9f

typedef __bf16 bf16x8 __attribute__((ext_vector_type(8)));
typedef float  f32x4  __attribute__((ext_vector_type(4)));

static __device__ __forceinline__ float bf2f(unsigned short h) {
    union { unsigned int u; float f; } c; c.u = ((unsigned int)h) << 16;
    return c.f;
}
static __device__ __forceinline__ unsigned short f2bf(float f) {
    union { float f; unsigned int u; } c; c.f = f;
    unsigned int u = c.u + 0x7fffu + ((c.u >> 16) & 1u);
    return (unsigned short)(u >> 16);
}

// ---------------- W transpose to bf16 (tiny, once) ----------------
__global__ __launch_bounds__(256) void transpose_w_kernel(
    const float* __restrict__ attn_W, const float* __restrict__ gate_W,
    __bf16* __restrict__ wta, __bf16* __restrict__ wtg)
{
    int i = blockIdx.x * 256 + threadIdx.x;
    if (i < 128 * 128) {
        int k = i >> 7, n = i & 127;
        wta[n * 128 + k] = (__bf16)attn_W[i];
    }
    if (i < 256 * 128) {
        int k = i >> 7, n = i & 127;
        wtg[n * 256 + k] = (__bf16)gate_W[i];
    }
}

// ---------------- keys = bf16( prev @ attn_W + attn_b ), MFMA ----------------
__global__ __launch_bounds__(256) void keys_mfma_kernel(
    const float* __restrict__ prev, const __bf16* __restrict__ wta,
    const float* __restrict__ attn_b, unsigned short* __restrict__ keysb, int N)
{
    const int lane = threadIdx.x & 63;
    const int wid  = threadIdx.x >> 6;
    const int m0 = (blockIdx.x * 4 + wid) * 16;
    if (m0 >= N) return;
    const int lm = lane & 15;
    const int lg = lane >> 4;

    int arow = m0 + lm; if (arow >= N) arow = m0;
    const float* ap = prev + (size_t)arow * D + lg * 8;

    f32x4 acc[8] = {};
    #pragma unroll
    for (int kk = 0; kk < 4; ++kk) {
        float4 a0 = *(const float4*)(ap + kk * 32);
        float4 a1 = *(const float4*)(ap + kk * 32 + 4);
        bf16x8 af;
        af[0] = (__bf16)a0.x; af[1] = (__bf16)a0.y; af[2] = (__bf16)a0.z; af[3] = (__bf16)a0.w;
        af[4] = (__bf16)a1.x; af[5] = (__bf16)a1.y; af[6] = (__bf16)a1.z; af[7] = (__bf16)a1.w;
        const int k0 = kk * 32;
        #pragma unroll
        for (int t = 0; t < 8; ++t) {
            bf16x8 bf_ = *(const bf16x8*)(wta + (size_t)(t * 16 + lm) * 128 + k0 + lg * 8);
            acc[t] = __builtin_amdgcn_mfma_f32_16x16x32_bf16(af, bf_, acc[t], 0, 0, 0);
        }
    }
    __bf16* kb = (__bf16*)keysb;
    #pragma unroll
    for (int t = 0; t < 8; ++t) {
        float bcol = attn_b[t * 16 + lm];
        #pragma unroll
        for (int r = 0; r < 4; ++r) {
            int row = m0 + lg * 4 + r;
            if (row < N)
                kb[(size_t)row * D + t * 16 + lm] = (__bf16)(acc[t][r] + bcol);
        }
    }
}

// ---------------- CSR build ----------------
__global__ __launch_bounds__(256) void hist_kernel(
    const int* __restrict__ idx3, const int* __restrict__ idx5,
    int* __restrict__ cnt, int E3, int E)
{
    int e = blockIdx.x * 256 + threadIdx.x;
    if (e >= E) return;
    int n = (e < E3) ? idx3[e] : idx5[e - E3];
    atomicAdd(&cnt[n], 1);
}

__global__ __launch_bounds__(256) void scan1_kernel(
    const int* __restrict__ cnt, int* __restrict__ row_start,
    int* __restrict__ bsum, int N)
{
    __shared__ int tsum[256];
    const int t = threadIdx.x;
    const int base = blockIdx.x * 1024;
    const int i0 = base + t * 4;
    int v0 = 0, v1 = 0, v2 = 0, v3 = 0;
    if (i0 + 0 < N) v0 = cnt[i0 + 0];
    if (i0 + 1 < N) v1 = cnt[i0 + 1];
    if (i0 + 2 < N) v2 = cnt[i0 + 2];
    if (i0 + 3 < N) v3 = cnt[i0 + 3];
    int s = v0 + v1 + v2 + v3;
    tsum[t] = s;
    __syncthreads();
    int val = s;
    for (int off = 1; off < 256; off <<= 1) {
        int tmp = (t >= off) ? tsum[t - off] : 0;
        __syncthreads();
        val += tmp; tsum[t] = val;
        __syncthreads();
    }
    int excl = val - s;
    if (i0 + 0 < N) row_start[i0 + 0] = excl;            excl += v0;
    if (i0 + 1 < N) row_start[i0 + 1] = excl;            excl += v1;
    if (i0 + 2 < N) row_start[i0 + 2] = excl;            excl += v2;
    if (i0 + 3 < N) row_start[i0 + 3] = excl;
    if (t == 255) bsum[blockIdx.x] = val;
}

__global__ __launch_bounds__(1024) void scan2_kernel(int* __restrict__ bsum, int nb)
{
    __shared__ int sh[1024];
    const int t = threadIdx.x;
    int v = (t < nb) ? bsum[t] : 0;
    sh[t] = v;
    __syncthreads();
    int val = v;
    for (int off = 1; off < 1024; off <<= 1) {
        int tmp = (t >= off) ? sh[t - off] : 0;
        __syncthreads();
        val += tmp; sh[t] = val;
        __syncthreads();
    }
    if (t < nb) bsum[t] = val - v;
}

__global__ __launch_bounds__(256) void scan3_kernel(
    int* __restrict__ row_start, const int* __restrict__ bsum, int N, int E)
{
    int i = blockIdx.x * 256 + threadIdx.x;
    if (i < N)       row_start[i] += bsum[i >> 10];
    else if (i == N) row_start[N] = E;
}

__global__ __launch_bounds__(256) void scatter_kernel(
    const int* __restrict__ idx3, const int* __restrict__ idx5,
    const int* __restrict__ row_start, int* __restrict__ cursor,
    int* __restrict__ edge_ids, int E3, int E)
{
    int e = blockIdx.x * 256 + threadIdx.x;
    if (e >= E) return;
    int n = (e < E3) ? idx3[e] : idx5[e - E3];
    int p = row_start[n] + atomicAdd(&cursor[n], 1);
    edge_ids[p] = e;
}

// ---------------- per-node attention aggregate ----------------
// one 64-lane wave per node. 32 lanes per edge (f32x4 = 16B/lane), two edges
// processed side-by-side (side = lane>>5); 8 independent 16B loads in flight
// per lane -> 16 edges per inner iteration. shfl_xor masks {1..16} stay
// within each 32-lane half; final shfl_xor(32) merges the two halves.
__global__ __launch_bounds__(256) void agg_kernel(
    const float* __restrict__ occ3, const float* __restrict__ occ5,
    const unsigned short* __restrict__ keysb,
    const int* __restrict__ row_start, const int* __restrict__ edge_ids,
    unsigned short* __restrict__ aggb, int E3, int N)
{
    const int lane = threadIdx.x & 63;
    const int wid  = threadIdx.x >> 6;
    const int n = blockIdx.x * 4 + wid;
    if (n >= N) return;

    const int hl   = lane & 31;
    const int side = lane >> 5;

    ushort4 kp = *(const ushort4*)(keysb + (size_t)n * D + hl * 4);
    float k0 = bf2f(kp.x), k1 = bf2f(kp.y), k2 = bf2f(kp.z), k3 = bf2f(kp.w);

    const int rs = row_start[n];
    const int re = row_start[n + 1];
    const float scale = 0.0883883476483184f;   // 1/sqrt(128)

    float a0 = 0.f, a1 = 0.f, a2 = 0.f, a3 = 0.f, den = 0.f;

    for (int base = rs; base < re; base += 64) {
        const int left = re - base;
        const int cnt = left < 64 ? left : 64;
        int myid = (lane < cnt) ? edge_ids[base + lane] : 0;

        for (int q0 = 0; q0 < cnt; q0 += 16) {
            f32x4 v[8];
            #pragma unroll
            for (int j = 0; j < 8; ++j) {
                int slot = q0 + 2 * j + side;
                int e = __shfl(myid, slot);                // slot<64; invalid -> id 0 (safe)
                const f32x4* vp = (e < E3)
                    ? (const f32x4*)(occ3 + (size_t)e * D)
                    : (const f32x4*)(occ5 + (size_t)(e - E3) * D);
                v[j] = __builtin_nontemporal_load(&vp[hl]);
            }
            float s[8];
            #pragma unroll
            for (int j = 0; j < 8; ++j)
                s[j] = v[j][0] * k0 + v[j][1] * k1 + v[j][2] * k2 + v[j][3] * k3;
            #pragma unroll
            for (int sh = 16; sh >= 1; sh >>= 1) {
                #pragma unroll
                for (int j = 0; j < 8; ++j)
                    s[j] += __shfl_xor(s[j], sh);          // stays within 32-lane half
            }
            #pragma unroll
            for (int j = 0; j < 8; ++j) {
                int slot = q0 + 2 * j + side;
                float ex = (slot < cnt) ? __expf(s[j] * scale) : 0.f;
                den += ex;
                a0 = fmaf(ex, v[j][0], a0);
                a1 = fmaf(ex, v[j][1], a1);
                a2 = fmaf(ex, v[j][2], a2);
                a3 = fmaf(ex, v[j][3], a3);
            }
        }
    }

    // merge even/odd-edge halves (lane l <-> l^32 hold same dims)
    den += __shfl_xor(den, 32);
    a0 += __shfl_xor(a0, 32);
    a1 += __shfl_xor(a1, 32);
    a2 += __shfl_xor(a2, 32);
    a3 += __shfl_xor(a3, 32);

    if (side == 0) {
        float inv = 1.0f / (den + EPSF);
        ushort4 o;
        o.x = f2bf(a0 * inv); o.y = f2bf(a1 * inv);
        o.z = f2bf(a2 * inv); o.w = f2bf(a3 * inv);
        *(ushort4*)(aggb + (size_t)n * D + hl * 4) = o;
    }
}

// ---------------- gate via MFMA ----------------
// z = sigmoid([prev | aggn] @ gate_W + b); out = z*aggn + (1-z)*prev.
// aggn is bf16 in ws (direct MFMA A-fragments); out = d_out, write-only.
__global__ __launch_bounds__(256) void gate_mfma_kernel(
    const float* __restrict__ prev, const __bf16* __restrict__ aggb,
    const __bf16* __restrict__ wtg, const float* __restrict__ gate_b,
    float* __restrict__ out, int N)
{
    const int lane = threadIdx.x & 63;
    const int wid  = threadIdx.x >> 6;
    const int m0 = (blockIdx.x * 4 + wid) * 16;
    if (m0 >= N) return;
    const int lm = lane & 15;
    const int lg = lane >> 4;

    int arow = m0 + lm; if (arow >= N) arow = m0;
    const float*  aprev = prev + (size_t)arow * D + lg * 8;
    const __bf16* aagg  = aggb + (size_t)arow * D + lg * 8;

    f32x4 acc[8] = {};
    #pragma unroll
    for (int kk = 0; kk < 4; ++kk) {
        float4 a0 = *(const float4*)(aprev + kk * 32);
        float4 a1 = *(const float4*)(aprev + kk * 32 + 4);
        bf16x8 af;
        af[0] = (__bf16)a0.x; af[1] = (__bf16)a0.y; af[2] = (__bf16)a0.z; af[3] = (__bf16)a0.w;
        af[4] = (__bf16)a1.x; af[5] = (__bf16)a1.y; af[6] = (__bf16)a1.z; af[7] = (__bf16)a1.w;
        const int k0 = kk * 32;
        #pragma unroll
        for (int t = 0; t < 8; ++t) {
            bf16x8 bf_ = *(const bf16x8*)(wtg + (size_t)(t * 16 + lm) * 256 + k0 + lg * 8);
            acc[t] = __builtin_amdgcn_mfma_f32_16x16x32_bf16(af, bf_, acc[t], 0, 0, 0);
        }
    }
    #pragma unroll
    for (int kk = 0; kk < 4; ++kk) {
        bf16x8 af = *(const bf16x8*)(aagg + kk * 32);
        const int k0 = 128 + kk * 32;
        #pragma unroll
        for (int t = 0; t < 8; ++t) {
            bf16x8 bf_ = *(const bf16x8*)(wtg + (size_t)(t * 16 + lm) * 256 + k0 + lg * 8);
            acc[t] = __builtin_amdgcn_mfma_f32_16x16x32_bf16(af, bf_, acc[t], 0, 0, 0);
        }
    }

    const unsigned short* aggu = (const unsigned short*)aggb;
    #pragma unroll
    for (int t = 0; t < 8; ++t) {
        float bcol = gate_b[t * 16 + lm];
        #pragma unroll
        for (int r = 0; r < 4; ++r) {
            int row = m0 + lg * 4 + r;
            if (row < N) {
                size_t off = (size_t)row * D + t * 16 + lm;
                float c = acc[t][r] + bcol;
                float z = 1.0f / (1.0f + __expf(-c));
                float a = bf2f(aggu[off]);
                float p = prev[off];
                out[off] = fmaf(z, a - p, p);
            }
        }
    }
}

extern "C" void kernel_launch(void* const* d_in, const int* in_sizes, int n_in,
                              void* d_out, int out_size, void* d_ws, size_t ws_size,
                              hipStream_t stream)
{
    const float* occ3   = (const float*)d_in[0];
    const int*   idx3   = (const int*)d_in[1];
    const float* occ5   = (const float*)d_in[2];
    const int*   idx5   = (const int*)d_in[3];
    const float* prev   = (const float*)d_in[4];
    const float* attn_W = (const float*)d_in[5];
    const float* attn_b = (const float*)d_in[6];
    const float* gate_W = (const float*)d_in[7];
    const float* gate_b = (const float*)d_in[8];

    const int N  = in_sizes[4] / D;
    const int E3 = in_sizes[1];
    const int E5 = in_sizes[3];
    const int E  = E3 + E5;

    // ws: keysb(bf16 N*D) | aggb(bf16 N*D) | row_start(N+1) | cnt(N) | cursor(N) | bsum(1025) | edge_ids(E) | wta | wtg
    unsigned short* keysb = (unsigned short*)d_ws;
    unsigned short* aggb  = keysb + (size_t)N * D;
    int* row_start = (int*)(aggb + (size_t)N * D);
    int* cnt       = row_start + (N + 1);
    int* cursor    = cnt + N;
    int* bsum      = cursor + N;
    int* edge_ids  = bsum + 1025;
    __bf16* wta    = (__bf16*)(edge_ids + E);
    __bf16* wtg    = wta + 128 * 128;

    float* out = (float*)d_out;

    (void)hipMemsetAsync(cnt, 0, (size_t)2 * N * sizeof(int), stream);  // cnt + cursor

    transpose_w_kernel<<<128, 256, 0, stream>>>(attn_W, gate_W, wta, wtg);

    const int nb = (N + 1023) / 1024;
    hist_kernel   <<<(E + 255) / 256, 256, 0, stream>>>(idx3, idx5, cnt, E3, E);
    scan1_kernel  <<<nb, 256, 0, stream>>>(cnt, row_start, bsum, N);
    scan2_kernel  <<<1, 1024, 0, stream>>>(bsum, nb);
    scan3_kernel  <<<(N + 256) / 256, 256, 0, stream>>>(row_start, bsum, N, E);
    scatter_kernel<<<(E + 255) / 256, 256, 0, stream>>>(idx3, idx5, row_start, cursor, edge_ids, E3, E);

    keys_mfma_kernel<<<(N + 63) / 64, 256, 0, stream>>>(prev, wta, attn_b, keysb, N);

    agg_kernel<<<(N + 3) / 4, 256, 0, stream>>>(occ3, occ5, keysb, row_start, edge_ids, aggb, E3, N);

    gate_mfma_kernel<<<(N + 63) / 64, 256, 0, stream>>>(prev, (const __bf16*)aggb, wtg, gate_b, out, N);
}